// Round 1
// baseline (2426.404 us; speedup 1.0000x reference)
//
#include <hip/hip_runtime.h>
#include <math.h>

#define Bn 64
#define Tn 291
#define Dn 300
#define Hn 10
#define Mn (Bn*Tn)   // 18624

static __device__ __forceinline__ float leaky(float x){ return x >= 0.f ? x : 0.01f*x; }

template<int NT>
static __device__ __forceinline__ float blockSum(float v, float* red){
  __syncthreads();
  int lane = threadIdx.x & 63, wid = threadIdx.x >> 6;
  #pragma unroll
  for (int o = 32; o > 0; o >>= 1) v += __shfl_down(v, o, 64);
  if (lane == 0) red[wid] = v;
  __syncthreads();
  if (threadIdx.x == 0) {
    float s = red[0];
    #pragma unroll
    for (int w = 1; w < NT/64; ++w) s += red[w];
    red[0] = s;
  }
  __syncthreads();
  return red[0];
}

template<int NT>
static __device__ __forceinline__ float blockMax(float v, float* red){
  __syncthreads();
  int lane = threadIdx.x & 63, wid = threadIdx.x >> 6;
  #pragma unroll
  for (int o = 32; o > 0; o >>= 1) v = fmaxf(v, __shfl_down(v, o, 64));
  if (lane == 0) red[wid] = v;
  __syncthreads();
  if (threadIdx.x == 0) {
    float s = red[0];
    #pragma unroll
    for (int w = 1; w < NT/64; ++w) s = fmaxf(s, red[w]);
    red[0] = s;
  }
  __syncthreads();
  return red[0];
}

// ---- image branch: y = leaky(x2 @ Wimg.T + bimg); lnP = LN_300(y)*g2+be2 ----
__global__ __launch_bounds__(256)
void k_img_lnp(const float* __restrict__ x2, const float* __restrict__ Wimg,
               const float* __restrict__ bimg, const float* __restrict__ g2,
               const float* __restrict__ be2, float* __restrict__ lnP)
{
  int b = blockIdx.x, tid = threadIdx.x;
  __shared__ float sx[1000];
  __shared__ float sy[300];
  __shared__ float red[4];
  for (int i = tid; i < 1000; i += 256) sx[i] = x2[b*1000 + i];
  __syncthreads();
  for (int j = tid; j < 300; j += 256) {
    const float* w = Wimg + j*1000;
    float a = 0.f;
    for (int i = 0; i < 1000; ++i) a += sx[i]*w[i];
    sy[j] = leaky(a + bimg[j]);
  }
  __syncthreads();
  float s = 0.f, ss = 0.f;
  for (int j = tid; j < 300; j += 256) { float v = sy[j]; s += v; ss += v*v; }
  float tot  = blockSum<256>(s, red);
  float tot2 = blockSum<256>(ss, red);
  float mu   = tot * (1.f/300.f);
  float var  = tot2 * (1.f/300.f) - mu*mu;
  float rstd = rsqrtf(var + 1e-5f);
  for (int j = tid; j < 300; j += 256)
    lnP[b*300 + j] = (sy[j]-mu)*rstd*g2[j] + be2[j];
}

// ---- lnT: LayerNorm over (291,300) per batch sample ----
__global__ __launch_bounds__(1024)
void k_lnT(const float* __restrict__ x1, const float* __restrict__ g1,
           const float* __restrict__ be1, float* __restrict__ out)
{
  int b = blockIdx.x, tid = threadIdx.x;
  __shared__ float red[16];
  const float4* xb = (const float4*)(x1 + (size_t)b*87300);
  const float4* g4 = (const float4*)g1;
  const float4* b4 = (const float4*)be1;
  float4* o4 = (float4*)(out + (size_t)b*87300);
  float s = 0.f, ss = 0.f;
  for (int i = tid; i < 21825; i += 1024) {
    float4 v = xb[i];
    s  += v.x+v.y+v.z+v.w;
    ss += v.x*v.x+v.y*v.y+v.z*v.z+v.w*v.w;
  }
  float tot  = blockSum<1024>(s, red);
  float tot2 = blockSum<1024>(ss, red);
  float mu   = tot / 87300.f;
  float var  = tot2 / 87300.f - mu*mu;
  float rstd = rsqrtf(var + 1e-5f);
  for (int i = tid; i < 21825; i += 1024) {
    float4 v = xb[i], g = g4[i], be = b4[i], o;
    o.x = (v.x-mu)*rstd*g.x + be.x;
    o.y = (v.y-mu)*rstd*g.y + be.y;
    o.z = (v.z-mu)*rstd*g.z + be.z;
    o.w = (v.w-mu)*rstd*g.w + be.w;
    o4[i] = o;
  }
}

// ---- T->P cross attention (single query) + v for P->T branch ----
__global__ __launch_bounds__(320)
void k_tp(const float* __restrict__ lnP, const float* __restrict__ lnT,
          const float* __restrict__ Wq, const float* __restrict__ Wk,
          const float* __restrict__ Wv, const float* __restrict__ Wvpt,
          float* __restrict__ RTP, float* __restrict__ vpt)
{
  int b = blockIdx.x, tid = threadIdx.x;
  __shared__ float sP[300], sQ[300], sM[300], sA[291], sW[300], red[5];
  if (tid < 300) sP[tid] = lnP[b*300 + tid];
  __syncthreads();
  if (tid < 300) {
    const float* w = Wq + tid*300;
    float a = 0.f;
    for (int i = 0; i < 300; ++i) a += sP[i]*w[i];
    sQ[tid] = a;
  }
  __syncthreads();
  if (tid < 300) {   // m = Wk.T @ q  (coalesced row-wise walk of Wk)
    float a = 0.f;
    for (int j = 0; j < 300; ++j) a += sQ[j]*Wk[j*300 + tid];
    sM[tid] = a;
  }
  __syncthreads();
  float sc = -1e30f;
  if (tid < 291) {
    const float* r = lnT + ((size_t)b*Tn + tid)*300;
    float a = 0.f;
    for (int i = 0; i < 300; ++i) a += r[i]*sM[i];
    sc = a;
  }
  float mx  = blockMax<320>(sc, red);
  float e   = (tid < 291) ? __expf(sc - mx) : 0.f;
  float den = blockSum<320>(e, red);
  if (tid < 291) sA[tid] = e;
  __syncthreads();
  if (tid < 300) {   // w = sum_t a_t * lnT[b,t,:]
    float a = 0.f;
    for (int t = 0; t < 291; ++t) a += sA[t]*lnT[((size_t)b*Tn + t)*300 + tid];
    sW[tid] = a / den;
  }
  __syncthreads();
  if (tid < 300) {
    const float* w = Wv + tid*300;
    float a = 0.f;
    for (int i = 0; i < 300; ++i) a += sW[i]*w[i];
    RTP[b*300 + tid] = a + sP[tid];
    const float* w2 = Wvpt + tid*300;
    float a2 = 0.f;
    for (int i = 0; i < 300; ++i) a2 += sP[i]*w2[i];
    vpt[b*300 + tid] = a2;
  }
}

// ---- rpt = lnT + vpt (broadcast over t) ----
__global__ __launch_bounds__(256)
void k_rpt(const float* __restrict__ lnT, const float* __restrict__ vpt,
           float* __restrict__ rpt)
{
  int idx = blockIdx.x*256 + threadIdx.x;
  if (idx >= Mn*Dn/4) return;
  int row = idx / 75;   // 75 float4 per 300-wide row
  int c4  = idx % 75;
  int b   = row / Tn;
  float4 v = ((const float4*)vpt)[b*75 + c4];
  float4 x = ((const float4*)lnT)[idx];
  float4 o; o.x = x.x+v.x; o.y = x.y+v.y; o.z = x.z+v.z; o.w = x.w+v.w;
  ((float4*)rpt)[idx] = o;
}

// ---- pack conv weights: Wp[c][r][300], r over (head,o,dh); 250 rows per channel ----
__global__ __launch_bounds__(256)
void k_pack(const float* __restrict__ Wc1, const float* __restrict__ Wc2,
            const float* __restrict__ Wc3, const float* __restrict__ Wc4,
            float* __restrict__ Wp)
{
  int idx = blockIdx.x*256 + threadIdx.x;
  if (idx >= 2*250*300) return;
  int d  = idx % 300;
  int rc = idx / 300;
  int c  = rc / 250;
  int r  = rc % 250;
  const float* W; int kh, ro;
  if      (r < 25)  { W = Wc1; kh = 1; ro = r;      }
  else if (r < 75)  { W = Wc2; kh = 2; ro = r - 25; }
  else if (r < 150) { W = Wc3; kh = 3; ro = r - 75; }
  else              { W = Wc4; kh = 4; ro = r - 150;}
  int o = ro / kh, dh = ro % kh;
  Wp[idx] = W[((o*2 + c)*kh + dh)*300 + d];
}

// ---- generic NT GEMM: C[m,n] = sum_k A[m,k]*W[n,k]; K=300, M=18624, z selects (A,W,C) ----
#define GBM 64
#define GBN 64
#define GBK 20
__global__ __launch_bounds__(256)
void k_gemm(const float* __restrict__ A0, const float* __restrict__ A1, const float* __restrict__ A2,
            const float* __restrict__ W0, const float* __restrict__ W1, const float* __restrict__ W2,
            float* __restrict__ C0, float* __restrict__ C1, float* __restrict__ C2,
            int N)
{
  const float* A = (blockIdx.z == 0) ? A0 : (blockIdx.z == 1) ? A1 : A2;
  const float* W = (blockIdx.z == 0) ? W0 : (blockIdx.z == 1) ? W1 : W2;
  float*       C = (blockIdx.z == 0) ? C0 : (blockIdx.z == 1) ? C1 : C2;
  int m0 = blockIdx.x*GBM, n0 = blockIdx.y*GBN;
  __shared__ float As[GBK][GBM+4];
  __shared__ float Bs[GBK][GBN+4];
  int tid = threadIdx.x;
  int tn = tid & 15, tm = tid >> 4;
  float acc[4][4] = {};
  for (int k0 = 0; k0 < 300; k0 += GBK) {
    #pragma unroll
    for (int u = 0; u < 5; ++u) {
      int i = tid + u*256;
      int r = i / GBK, c = i % GBK;
      As[c][r] = A[(size_t)(m0 + r)*300 + k0 + c];
      int n = n0 + r;
      Bs[c][r] = (n < N) ? W[(size_t)n*300 + k0 + c] : 0.f;
    }
    __syncthreads();
    #pragma unroll
    for (int kk = 0; kk < GBK; ++kk) {
      float4 av = *reinterpret_cast<const float4*>(&As[kk][tm*4]);
      float4 bv = *reinterpret_cast<const float4*>(&Bs[kk][tn*4]);
      float a[4] = {av.x, av.y, av.z, av.w};
      float bb[4] = {bv.x, bv.y, bv.z, bv.w};
      #pragma unroll
      for (int i = 0; i < 4; ++i)
        #pragma unroll
        for (int j = 0; j < 4; ++j)
          acc[i][j] += a[i]*bb[j];
    }
    __syncthreads();
  }
  #pragma unroll
  for (int i = 0; i < 4; ++i) {
    int m = m0 + tm*4 + i;
    #pragma unroll
    for (int j = 0; j < 4; ++j) {
      int n = n0 + tn*4 + j;
      if (n < N) C[(size_t)m*N + n] = acc[i][j];
    }
  }
}

// ---- per-(b,h) self-attention, online softmax, 1 thread per query row ----
__global__ __launch_bounds__(320)
void k_attn(const float* __restrict__ Q, const float* __restrict__ Kb,
            const float* __restrict__ Vb, float* __restrict__ O)
{
  int b = blockIdx.x, h = blockIdx.y, tid = threadIdx.x;
  __shared__ float Ks[Tn][32];
  __shared__ float Vs[Tn][32];
  const size_t base = (size_t)b*Tn*300 + h*30;
  for (int i = tid; i < Tn*32; i += 320) {
    int t = i >> 5, k = i & 31;
    float kv = 0.f, vv = 0.f;
    if (k < 30) {
      kv = Kb[base + (size_t)t*300 + k];
      vv = Vb[base + (size_t)t*300 + k];
    }
    Ks[t][k] = kv; Vs[t][k] = vv;
  }
  __syncthreads();
  if (tid < Tn) {
    float q[32];
    const float* qp = Q + base + (size_t)tid*300;
    #pragma unroll
    for (int k = 0; k < 30; ++k) q[k] = qp[k];
    q[30] = 0.f; q[31] = 0.f;
    float m = -1e30f, l = 0.f, acc[32];
    #pragma unroll
    for (int k = 0; k < 32; ++k) acc[k] = 0.f;
    const float scale = 0.31622776601683794f;  // 1/sqrt(H)
    for (int j = 0; j < Tn; ++j) {
      const float4* kr = (const float4*)Ks[j];
      float s = 0.f;
      #pragma unroll
      for (int k4 = 0; k4 < 8; ++k4) {
        float4 kv = kr[k4];
        s += q[k4*4+0]*kv.x + q[k4*4+1]*kv.y + q[k4*4+2]*kv.z + q[k4*4+3]*kv.w;
      }
      s *= scale;
      if (s > m) {
        float f = __expf(m - s);
        l *= f;
        #pragma unroll
        for (int k = 0; k < 32; ++k) acc[k] *= f;
        m = s;
      }
      float p = __expf(s - m);
      l += p;
      const float4* vr = (const float4*)Vs[j];
      #pragma unroll
      for (int k4 = 0; k4 < 8; ++k4) {
        float4 vv = vr[k4];
        acc[k4*4+0] += p*vv.x; acc[k4*4+1] += p*vv.y;
        acc[k4*4+2] += p*vv.z; acc[k4*4+3] += p*vv.w;
      }
    }
    float inv = 1.f/l;
    float* op = O + base + (size_t)tid*300;
    #pragma unroll
    for (int k = 0; k < 30; ++k) op[k] = acc[k]*inv;
  }
}

// ---- conv head reduce: y[b,o,l] = bias + sum_{c,dh} G_c[b*291+l+dh, col]; leaky; max_l ----
__global__ __launch_bounds__(256)
void k_convred(const float* __restrict__ G0, const float* __restrict__ G1,
               const float* __restrict__ bc1, const float* __restrict__ bc2,
               const float* __restrict__ bc3, const float* __restrict__ bc4,
               float* __restrict__ out100)
{
  __shared__ float red[4];
  int b = blockIdx.x, head = blockIdx.y;
  int kh  = head + 1;
  int off = (head == 0) ? 0 : (head == 1) ? 25 : (head == 2) ? 75 : 150;
  const float* bc = (head == 0) ? bc1 : (head == 1) ? bc2 : (head == 2) ? bc3 : bc4;
  int L = Tn - kh + 1;
  int tid = threadIdx.x;
  for (int o = 0; o < 25; ++o) {
    float bias = bc[o];
    float mx = -1e30f;
    for (int l = tid; l < L; l += 256) {
      float s = bias;
      for (int dh = 0; dh < kh; ++dh) {
        size_t row = (size_t)(b*Tn + l + dh)*250 + off + o*kh + dh;
        s += G0[row] + G1[row];
      }
      mx = fmaxf(mx, leaky(s));
    }
    mx = blockMax<256>(mx, red);
    if (tid == 0) out100[b*100 + head*25 + o] = mx;
  }
}

// ---- final: total = leaky(out100 @ Wlin.T + blin); Y = [RTP, total] @ Wlast.T + blast ----
__global__ __launch_bounds__(320)
void k_final(const float* __restrict__ RTP, const float* __restrict__ out100,
             const float* __restrict__ Wlin, const float* __restrict__ blin,
             const float* __restrict__ Wlast, const float* __restrict__ blast,
             float* __restrict__ Y)
{
  int b = blockIdx.x, tid = threadIdx.x;
  __shared__ float cat[600];
  __shared__ float s100[100];
  __shared__ float red[5];
  if (tid < 100) s100[tid] = out100[b*100 + tid];
  if (tid < 300) cat[tid] = RTP[b*300 + tid];
  __syncthreads();
  if (tid < 300) {
    const float* w = Wlin + tid*100;
    float a = blin[tid];
    for (int j = 0; j < 100; ++j) a += s100[j]*w[j];
    cat[300 + tid] = leaky(a);
  }
  __syncthreads();
  for (int c = 0; c < 2; ++c) {
    float a = 0.f;
    for (int i = tid; i < 600; i += 320) a += cat[i]*Wlast[c*600 + i];
    a = blockSum<320>(a, red);
    if (tid == 0) Y[b*2 + c] = a + blast[c];
  }
}

extern "C" void kernel_launch(void* const* d_in, const int* in_sizes, int n_in,
                              void* d_out, int out_size, void* d_ws, size_t ws_size,
                              hipStream_t stream)
{
  (void)in_sizes; (void)n_in; (void)out_size; (void)ws_size;
  const float* x1    = (const float*)d_in[0];
  const float* x2    = (const float*)d_in[1];
  const float* Wimg  = (const float*)d_in[2];
  const float* bimg  = (const float*)d_in[3];
  const float* g1    = (const float*)d_in[4];
  const float* be1   = (const float*)d_in[5];
  const float* g2    = (const float*)d_in[6];
  const float* be2   = (const float*)d_in[7];
  const float* Wq_tp = (const float*)d_in[8];
  const float* Wk_tp = (const float*)d_in[9];
  const float* Wv_tp = (const float*)d_in[10];
  // d_in[11], d_in[12]: Wq_pt, Wk_pt — mathematically dead (softmax over size-1 axis)
  const float* Wv_pt = (const float*)d_in[13];
  const float* Wq1 = (const float*)d_in[14];
  const float* Wk1 = (const float*)d_in[15];
  const float* Wv1 = (const float*)d_in[16];
  const float* Wm1 = (const float*)d_in[17];
  const float* Wq2 = (const float*)d_in[18];
  const float* Wk2 = (const float*)d_in[19];
  const float* Wv2 = (const float*)d_in[20];
  const float* Wm2 = (const float*)d_in[21];
  const float* Wq3 = (const float*)d_in[22];
  const float* Wk3 = (const float*)d_in[23];
  const float* Wv3 = (const float*)d_in[24];
  const float* Wm3 = (const float*)d_in[25];
  const float* Wc1 = (const float*)d_in[26];
  const float* Wc2 = (const float*)d_in[27];
  const float* Wc3 = (const float*)d_in[28];
  const float* Wc4 = (const float*)d_in[29];
  const float* bc1 = (const float*)d_in[30];
  const float* bc2 = (const float*)d_in[31];
  const float* bc3 = (const float*)d_in[32];
  const float* bc4 = (const float*)d_in[33];
  const float* Wlin  = (const float*)d_in[34];
  const float* blin  = (const float*)d_in[35];
  const float* Wlast = (const float*)d_in[36];
  const float* blast = (const float*)d_in[37];

  float* ws     = (float*)d_ws;
  float* lnP    = ws;             // 19200
  float* RTP    = ws + 19200;     // 19200
  float* vpt    = ws + 38400;     // 19200
  float* out100 = ws + 57600;     // 6400
  float* Wp     = ws + 64000;     // 150000 (2*250*300)
  const size_t BS = (size_t)Mn*Dn;  // 5,587,200 floats
  float* buf0 = ws + 262144;
  float* buf1 = buf0 + BS;
  float* buf2 = buf1 + BS;
  float* buf3 = buf2 + BS;
  float* buf4 = buf3 + BS;

  k_img_lnp<<<Bn, 256, 0, stream>>>(x2, Wimg, bimg, g2, be2, lnP);
  k_lnT<<<Bn, 1024, 0, stream>>>(x1, g1, be1, buf0);                 // buf0 = lnT
  k_tp<<<Bn, 320, 0, stream>>>(lnP, buf0, Wq_tp, Wk_tp, Wv_tp, Wv_pt, RTP, vpt);
  k_rpt<<<(Mn*Dn/4 + 255)/256, 256, 0, stream>>>(buf0, vpt, buf1);   // buf1 = R_P_T
  k_pack<<<(2*250*300 + 255)/256, 256, 0, stream>>>(Wc1, Wc2, Wc3, Wc4, Wp);

  dim3 gqkv(Mn/64, 5, 3), gone(Mn/64, 5, 1), gconv(Mn/64, 4, 2), gat(Bn, Hn);
  // MHA1: in=lnT(buf0) -> Q=buf2 K=buf3 V=buf4 ; O=buf0 ; a1=buf2
  k_gemm<<<gqkv, 256, 0, stream>>>(buf0,buf0,buf0, Wq1,Wk1,Wv1, buf2,buf3,buf4, 300);
  k_attn<<<gat, 320, 0, stream>>>(buf2, buf3, buf4, buf0);
  k_gemm<<<gone, 256, 0, stream>>>(buf0,buf0,buf0, Wm1,Wm1,Wm1, buf2,buf2,buf2, 300);
  // MHA2: in=a1(buf2) -> Q=buf0 K=buf3 V=buf4 ; O=buf2 ; a2=buf0
  k_gemm<<<gqkv, 256, 0, stream>>>(buf2,buf2,buf2, Wq2,Wk2,Wv2, buf0,buf3,buf4, 300);
  k_attn<<<gat, 320, 0, stream>>>(buf0, buf3, buf4, buf2);
  k_gemm<<<gone, 256, 0, stream>>>(buf2,buf2,buf2, Wm2,Wm2,Wm2, buf0,buf0,buf0, 300);
  // MHA3: in=a2(buf0) -> Q=buf2 K=buf3 V=buf4 ; O=buf0 ; a3=buf2
  k_gemm<<<gqkv, 256, 0, stream>>>(buf0,buf0,buf0, Wq3,Wk3,Wv3, buf2,buf3,buf4, 300);
  k_attn<<<gat, 320, 0, stream>>>(buf2, buf3, buf4, buf0);
  k_gemm<<<gone, 256, 0, stream>>>(buf0,buf0,buf0, Wm3,Wm3,Wm3, buf2,buf2,buf2, 300);
  // conv GEMMs: z0: G0(buf3) = rpt(buf1) @ Wp_c0.T ; z1: G1(buf4) = a3(buf2) @ Wp_c1.T
  k_gemm<<<gconv, 256, 0, stream>>>(buf1,buf2,buf1, Wp,Wp+75000,Wp, buf3,buf4,buf3, 250);
  k_convred<<<dim3(Bn,4), 256, 0, stream>>>(buf3, buf4, bc1, bc2, bc3, bc4, out100);
  k_final<<<Bn, 320, 0, stream>>>(RTP, out100, Wlin, blin, Wlast, blast, (float*)d_out);
}